// Round 4
// baseline (34613.153 us; speedup 1.0000x reference)
//
#include <hip/hip_runtime.h>
#include <math.h>

#define H 2048
#define S 8192
#define RPB 8            // hidden rows per block
#define NBLK (H / RPB)   // 256 blocks = 256 CUs

// ---------------------------------------------------------------------------
// GEMM: U[t][j] = sum_k X[t][k] * Wxh[j][k]   (NT, fp32 vector ALU). ~1.5 ms.
// ---------------------------------------------------------------------------
__global__ __launch_bounds__(256) void gemm_xw(const float* __restrict__ X,
                                               const float* __restrict__ W,
                                               float* __restrict__ U) {
    __shared__ float As[16][64];   // [k][t]
    __shared__ float Bs[16][64];   // [k][j]
    const int tid = threadIdx.x;
    const int t0 = blockIdx.x * 64;
    const int j0 = blockIdx.y * 64;
    const int tx = tid & 15, ty = tid >> 4;

    float acc[4][4] = {};
    const int lr = tid >> 2;
    const int lk = (tid & 3) * 4;

    for (int k0 = 0; k0 < H; k0 += 16) {
        float4 a = *(const float4*)&X[(size_t)(t0 + lr) * H + k0 + lk];
        float4 b = *(const float4*)&W[(size_t)(j0 + lr) * H + k0 + lk];
        As[lk + 0][lr] = a.x; As[lk + 1][lr] = a.y; As[lk + 2][lr] = a.z; As[lk + 3][lr] = a.w;
        Bs[lk + 0][lr] = b.x; Bs[lk + 1][lr] = b.y; Bs[lk + 2][lr] = b.z; Bs[lk + 3][lr] = b.w;
        __syncthreads();
#pragma unroll
        for (int kk = 0; kk < 16; ++kk) {
            float4 av = *(const float4*)&As[kk][ty * 4];
            float4 bv = *(const float4*)&Bs[kk][tx * 4];
            float aa[4] = {av.x, av.y, av.z, av.w};
            float bb[4] = {bv.x, bv.y, bv.z, bv.w};
#pragma unroll
            for (int i = 0; i < 4; ++i)
#pragma unroll
                for (int j = 0; j < 4; ++j)
                    acc[i][j] += aa[i] * bb[j];
        }
        __syncthreads();
    }
#pragma unroll
    for (int i = 0; i < 4; ++i) {
        float4 v = {acc[i][0], acc[i][1], acc[i][2], acc[i][3]};
        *(float4*)&U[(size_t)(t0 + ty * 4 + i) * H + j0 + tx * 4] = v;
    }
}

// ---------------------------------------------------------------------------
// Init tagged h double-buffer: entry = (tag<<32)|float_bits; all zero =>
// (tag=0, h=0) which is h0 for step 0; buffer 1's tag 0 never matches t>=1.
// ---------------------------------------------------------------------------
__global__ void init_ws(unsigned long long* __restrict__ hvt) {
    int i = blockIdx.x * blockDim.x + threadIdx.x;
    if (i < 2 * H) hvt[i] = 0ull;
}

#define AG_LOAD(p)     __hip_atomic_load((p), __ATOMIC_RELAXED, __HIP_MEMORY_SCOPE_AGENT)
#define AG_STORE(p, v) __hip_atomic_store((p), (v), __ATOMIC_RELAXED, __HIP_MEMORY_SCOPE_AGENT)

// ---------------------------------------------------------------------------
// Persistent recurrent kernel, data-flow sync on tagged (tag|value) words.
// Round-4 changes vs round-3 (critical-path surgery):
//  * PUBLISH FIRST: the sc1 tagged-h store is issued before the out[] write
//    (store queue is FIFO; out[] is a cold-HBM write-allocate miss that was
//    delaying publish visibility by ~1 us).
//  * U software pipeline: step t prefetches U[t+1] at step top; its ~1 us
//    HBM latency hides under the poll instead of landing in the first
//    poll-check's waitcnt.
//  * Staggered 2-deep polling, no s_sleep: two independent load batches
//    checked alternately -> checking batch A waits vmcnt only down to B's
//    outstanding count -> sampling period ~ load_latency/2.
// Skew bound unchanged: 2-deep tagged buffer race-free (max skew 1 step).
// ---------------------------------------------------------------------------
__global__ __launch_bounds__(256) void rnn_recur(float* __restrict__ out,
                                                 const float* __restrict__ Whh,
                                                 const float* __restrict__ bias,
                                                 unsigned long long* __restrict__ hvt) {
    __shared__ float Wl[RPB * H];   // 64 KB: this block's 8 rows of W_hh
    __shared__ float hs[2][H];      // 16 KB: ping-pong h_{t-1}
    const int tid = threadIdx.x;
    const int r0 = blockIdx.x * RPB;

    // Stage W rows into LDS (once).
    {
        const float4* src = (const float4*)&Whh[(size_t)r0 * H];
        float4* dst = (float4*)Wl;
        for (int i = tid; i < RPB * H / 4; i += 256) dst[i] = src[i];
    }

    const int g    = tid >> 5;   // row group 0..7 (aligned 32-lane segments)
    const int lane = tid & 31;
    const int row  = r0 + g;
    const float bb = bias[row];
    const float4* wr = (const float4*)&Wl[g * H];

    float u_next = out[row];     // U for step 0 (prefetched before loop)
    float hT = 0.0f;             // lane0: last h value for h_T epilogue

    for (int t = 0; t < S; ++t) {
        const float u_val = u_next;
        if (t + 1 < S)           // prefetch next step's U; hidden under poll
            u_next = out[(size_t)(t + 1) * H + row];

        // ---- data-flow wait: gather h_{t-1} (tag == t) into LDS ----
        const unsigned int tag = (unsigned int)t;
        unsigned long long* hb = &hvt[(size_t)(t & 1) * H];
        float* hdst = hs[t & 1];
        unsigned int pend = 0xFFu;
        unsigned long long va[8], vb[8];
#pragma unroll
        for (int i = 0; i < 8; ++i) va[i] = AG_LOAD(&hb[i * 256 + tid]);
#pragma unroll
        for (int i = 0; i < 8; ++i) vb[i] = AG_LOAD(&hb[i * 256 + tid]);
        while (pend) {
            // check batch A (waits only for A's loads; B stays in flight)
#pragma unroll
            for (int i = 0; i < 8; ++i)
                if (pend & (1u << i))
                    if ((unsigned int)(va[i] >> 32) == tag) {
                        hdst[i * 256 + tid] = __uint_as_float((unsigned int)va[i]);
                        pend &= ~(1u << i);
                    }
            if (!pend) break;
#pragma unroll
            for (int i = 0; i < 8; ++i)
                if (pend & (1u << i)) va[i] = AG_LOAD(&hb[i * 256 + tid]);
            // check batch B
#pragma unroll
            for (int i = 0; i < 8; ++i)
                if (pend & (1u << i))
                    if ((unsigned int)(vb[i] >> 32) == tag) {
                        hdst[i * 256 + tid] = __uint_as_float((unsigned int)vb[i]);
                        pend &= ~(1u << i);
                    }
            if (!pend) break;
#pragma unroll
            for (int i = 0; i < 8; ++i)
                if (pend & (1u << i)) vb[i] = AG_LOAD(&hb[i * 256 + tid]);
        }
        __syncthreads();   // hs[t&1] fully written before any dot reads it

        // ---- dot: 32 lanes x 64 elems per row ----
        const float4* hv = (const float4*)hdst;
        float dot = 0.f;
#pragma unroll
        for (int i = 0; i < 16; ++i) {
            float4 w  = wr[lane + i * 32];
            float4 h4 = hv[lane + i * 32];
            dot += w.x * h4.x + w.y * h4.y + w.z * h4.z + w.w * h4.w;
        }
#pragma unroll
        for (int off = 16; off; off >>= 1)
            dot += __shfl_down(dot, off, 32);

        if (lane == 0) {
            float val = tanhf(dot + u_val + bb);
            // PUBLISH FIRST (critical path): one 8B sc1 store.
            unsigned long long pk =
                ((unsigned long long)(unsigned int)(t + 1) << 32) |
                (unsigned long long)__float_as_uint(val);
            AG_STORE(&hvt[(size_t)((t + 1) & 1) * H + row], pk);
            // Off-critical-path: overwrite U with h_t.
            out[(size_t)t * H + row] = val;
            hT = val;
        }
        // No trailing barrier: next step polls the other LDS parity; cross-
        // block progress is gated by the tags themselves.
    }
    if (lane == 0) out[(size_t)S * H + row] = hT;   // h_T
}

extern "C" void kernel_launch(void* const* d_in, const int* in_sizes, int n_in,
                              void* d_out, int out_size, void* d_ws, size_t ws_size,
                              hipStream_t stream) {
    const float* X    = (const float*)d_in[0];  // (8192, 2048)
    const float* Wxh  = (const float*)d_in[1];  // (2048, 2048)
    const float* Whh  = (const float*)d_in[2];  // (2048, 2048)
    const float* bias = (const float*)d_in[3];  // (2048,)
    float* out = (float*)d_out;
    unsigned long long* hvt = (unsigned long long*)d_ws;   // 2*H tagged (32 KB)

    init_ws<<<(2 * H + 255) / 256, 256, 0, stream>>>(hvt);

    dim3 ggrid(S / 64, H / 64);
    gemm_xw<<<ggrid, 256, 0, stream>>>(X, Wxh, out);

    void* args[] = {(void*)&out, (void*)&Whh, (void*)&bias, (void*)&hvt};
    hipLaunchCooperativeKernel((void*)rnn_recur, dim3(NBLK), dim3(256), args, 0, stream);
}